// Round 1
// baseline (110.481 us; speedup 1.0000x reference)
//
#include <hip/hip_runtime.h>
#include <stdint.h>

#define NROWS 8192
#define DIM 128
#define NCHUNK 16      // j-chunks in mining grid
#define MARGIN 0.5f

typedef short short8 __attribute__((ext_vector_type(8)));   // 8 bf16 (4 VGPRs)
typedef float f32x4 __attribute__((ext_vector_type(4)));
typedef int   int4v __attribute__((ext_vector_type(4)));
typedef float f4v   __attribute__((ext_vector_type(4)));

static __device__ __forceinline__ unsigned short f2bf(float f) {
    union { float f; unsigned u; } x; x.f = f;
    unsigned u = x.u;
    return (unsigned short)((u + 0x7FFFu + ((u >> 16) & 1u)) >> 16);  // RNE
}

// ---------------------------------------------------------------------------
// prep: bf16 copy of embeds, c_j = sq_j + 512 (f32 exact), zero loss acc.
// One wave per row; lane handles 2 dims.
// ---------------------------------------------------------------------------
__global__ __launch_bounds__(256) void prep(const float* __restrict__ emb,
                                            unsigned short* __restrict__ e16,
                                            float* __restrict__ cbuf,
                                            float* __restrict__ acc) {
    const int lane = threadIdx.x & 63;
    const int row = blockIdx.x * 4 + (threadIdx.x >> 6);
    const float2 v = reinterpret_cast<const float2*>(emb + row * DIM)[lane];
    float sq = v.x * v.x + v.y * v.y;
#pragma unroll
    for (int m = 1; m < 64; m <<= 1) sq += __shfl_xor(sq, m, 64);
    const unsigned pack = ((unsigned)f2bf(v.y) << 16) | (unsigned)f2bf(v.x);
    *reinterpret_cast<unsigned*>(e16 + row * DIM + lane * 2) = pack;
    if (lane == 0) cbuf[row] = sq + 512.0f;
    if (blockIdx.x == 0 && threadIdx.x == 0) *acc = 0.0f;
}

// ---------------------------------------------------------------------------
// mine: fused Gram-GEMM + batch-hard mining.
// Grid: 32 i-blocks (256 rows each) x 16 j-chunks (512 cols each) = 512 blocks.
// Block: 256 thr = 4 waves; wave owns 4 i-tiles of 16, iterates 32 j-tiles.
// MFMA orientation: D[m=j][n=i] so lane's i (= lane&15) is fixed all kernel.
// Candidate packed as (g_bits & ~8191) | idxcode: u32 max/min tracks value+index.
//   pos code = 8191-j  (max, first-index tie-break)
//   neg code = j       (min, first-index tie-break)
// ---------------------------------------------------------------------------
__global__ __launch_bounds__(256) void mine(const unsigned short* __restrict__ e16,
                                            const float* __restrict__ cbuf,
                                            const int* __restrict__ labels,
                                            unsigned* __restrict__ pos_part,
                                            unsigned* __restrict__ neg_part) {
    const int tid  = threadIdx.x;
    const int wave = tid >> 6;
    const int lane = tid & 63;
    const int l15  = lane & 15;
    const int lhi  = lane >> 4;
    const int iblk = blockIdx.x & 31;
    const int cblk = blockIdx.x >> 5;
    const int ibase = iblk * 256 + wave * 64;

    // B operand (i side): held in registers for the whole kernel.
    short8 bfrag[4][4];
    int labi[4];
#pragma unroll
    for (int it = 0; it < 4; ++it) {
        const int row = ibase + it * 16 + l15;
#pragma unroll
        for (int ks = 0; ks < 4; ++ks)
            bfrag[it][ks] = *reinterpret_cast<const short8*>(e16 + row * DIM + ks * 32 + lhi * 8);
        labi[it] = labels[row];
    }

    unsigned bp[4], bn[4];
#pragma unroll
    for (int it = 0; it < 4; ++it) { bp[it] = 8191u; bn[it] = 0x7F800000u; }

    const int jcbase = cblk * 512;
    for (int t = 0; t < 32; ++t) {
        const int jb = jcbase + t * 16;
        short8 af[4];
#pragma unroll
        for (int ks = 0; ks < 4; ++ks)
            af[ks] = *reinterpret_cast<const short8*>(e16 + (jb + l15) * DIM + ks * 32 + lhi * 8);
        const int4v labj = *reinterpret_cast<const int4v*>(labels + jb + lhi * 4);
        const f4v   c4   = *reinterpret_cast<const f4v*>(cbuf + jb + lhi * 4);

        f32x4 acc[4];
        const f32x4 z = {0.f, 0.f, 0.f, 0.f};
#pragma unroll
        for (int it = 0; it < 4; ++it)
            acc[it] = __builtin_amdgcn_mfma_f32_16x16x32_bf16(af[0], bfrag[it][0], z, 0, 0, 0);
#pragma unroll
        for (int ks = 1; ks < 4; ++ks)
#pragma unroll
            for (int it = 0; it < 4; ++it)
                acc[it] = __builtin_amdgcn_mfma_f32_16x16x32_bf16(af[ks], bfrag[it][ks], acc[it], 0, 0, 0);

        const int j0 = jb + lhi * 4;             // this lane's 4 j's: j0..j0+3
        const unsigned pc0 = 8191u - (unsigned)j0;
        const unsigned nc0 = (unsigned)j0;
#pragma unroll
        for (int it = 0; it < 4; ++it) {
#pragma unroll
            for (int r = 0; r < 4; ++r) {
                const float g = fmaf(-2.0f, acc[it][r], c4[r]);  // 512+sq_j-2*dot > 0
                union { float f; unsigned u; } cv; cv.f = g;
                const unsigned u = cv.u & 0xFFFFE000u;
                const unsigned pcand = u | (pc0 - (unsigned)r);
                const unsigned ncand = u | (nc0 + (unsigned)r);
                const bool eq = (labj[r] == labi[it]);
                const unsigned psel = eq ? pcand : 0u;
                const unsigned nsel = eq ? 0x7F800000u : ncand;
                bp[it] = bp[it] > psel ? bp[it] : psel;
                bn[it] = bn[it] < nsel ? bn[it] : nsel;
            }
        }
    }

    // cross-lane: lanes {l, l^16, l^32, l^48} share the same i
#pragma unroll
    for (int it = 0; it < 4; ++it) {
        unsigned p = bp[it], n = bn[it];
        unsigned o;
        o = (unsigned)__shfl_xor((int)p, 16, 64); p = p > o ? p : o;
        o = (unsigned)__shfl_xor((int)p, 32, 64); p = p > o ? p : o;
        o = (unsigned)__shfl_xor((int)n, 16, 64); n = n < o ? n : o;
        o = (unsigned)__shfl_xor((int)n, 32, 64); n = n < o ? n : o;
        if (lane < 16) {
            pos_part[cblk * NROWS + ibase + it * 16 + lane] = p;
            neg_part[cblk * NROWS + ibase + it * 16 + lane] = n;
        }
    }
}

// ---------------------------------------------------------------------------
// lossk: combine 16 chunk-partials per row, extract indices, exact f32 ap/an,
// relu(ap-an+margin), block-reduced atomic into acc. One wave per row-iter.
// ---------------------------------------------------------------------------
__global__ __launch_bounds__(256) void lossk(const float* __restrict__ emb,
                                             const unsigned* __restrict__ pos_part,
                                             const unsigned* __restrict__ neg_part,
                                             float* __restrict__ acc) {
    __shared__ float wsum[4];
    const int tid = threadIdx.x, lane = tid & 63, wave = tid >> 6;
    const int w = blockIdx.x * 4 + wave;          // 0..1023
    float sum = 0.f;
    for (int itr = 0; itr < 8; ++itr) {
        const int i = itr * 1024 + w;
        unsigned p = pos_part[(lane & 15) * NROWS + i];
        unsigned n = neg_part[(lane & 15) * NROWS + i];
#pragma unroll
        for (int m = 1; m < 16; m <<= 1) {
            unsigned o;
            o = (unsigned)__shfl_xor((int)p, m, 64); p = p > o ? p : o;
            o = (unsigned)__shfl_xor((int)n, m, 64); n = n < o ? n : o;
        }
        const int jp = 8191 - (int)(p & 8191u);
        const int jn = (int)(n & 8191u);
        const float2 a = reinterpret_cast<const float2*>(emb + i  * DIM)[lane];
        const float2 b = reinterpret_cast<const float2*>(emb + jp * DIM)[lane];
        const float2 c = reinterpret_cast<const float2*>(emb + jn * DIM)[lane];
        float dx = a.x - b.x, dy = a.y - b.y;
        const float ap = dx * dx + dy * dy;
        dx = a.x - c.x; dy = a.y - c.y;
        const float an = dx * dx + dy * dy;
        float v = ap - an;
#pragma unroll
        for (int m = 1; m < 64; m <<= 1) v += __shfl_xor(v, m, 64);
        if (lane == 0) sum += fmaxf(v + MARGIN, 0.f);
    }
    if (lane == 0) wsum[wave] = sum;
    __syncthreads();
    if (tid == 0) atomicAdd(acc, wsum[0] + wsum[1] + wsum[2] + wsum[3]);
}

__global__ void fin(const float* __restrict__ acc, float* __restrict__ out) {
    out[0] = acc[0] * (1.0f / (float)NROWS);
}

// ---------------------------------------------------------------------------
extern "C" void kernel_launch(void* const* d_in, const int* in_sizes, int n_in,
                              void* d_out, int out_size, void* d_ws, size_t ws_size,
                              hipStream_t stream) {
    const float* emb   = (const float*)d_in[0];
    const int* labels  = (const int*)d_in[1];
    float* out = (float*)d_out;
    char* ws = (char*)d_ws;

    unsigned short* e16 = (unsigned short*)ws;                       // 2 MB
    float* cbuf         = (float*)(ws + 2097152);                    // 32 KB
    unsigned* pos_part  = (unsigned*)(ws + 2097152 + 32768);         // 512 KB
    unsigned* neg_part  = pos_part + NCHUNK * NROWS;                 // 512 KB
    float* acc          = (float*)(neg_part + NCHUNK * NROWS);       // 4 B

    prep<<<2048, 256, 0, stream>>>(emb, e16, cbuf, acc);
    mine<<<512, 256, 0, stream>>>(e16, cbuf, labels, pos_part, neg_part);
    lossk<<<256, 256, 0, stream>>>(emb, pos_part, neg_part, acc);
    fin<<<1, 1, 0, stream>>>(acc, out);
}